// Round 1
// baseline (666.040 us; speedup 1.0000x reference)
//
#include <hip/hip_runtime.h>
#include <math.h>

// GCN 5-layer: per layer relu(A @ (h @ W) + b), A = sym-normalized adj w/ self-loops.
// Strategy: CSR-by-dst build (no float atomics), aggregate on the narrow side of
// each GEMM, fold dinv[src] row-scaling into GEMM epilogues. All fp32.

__global__ __launch_bounds__(256) void k_count(const int* __restrict__ dst,
                                               int* __restrict__ deg, int E) {
    int e = blockIdx.x * 256 + threadIdx.x;
    if (e < E) atomicAdd(&deg[dst[e]], 1);
}

__global__ __launch_bounds__(256) void k_dinv(const int* __restrict__ deg,
                                              float* __restrict__ dinv, int n) {
    int i = blockIdx.x * 256 + threadIdx.x;
    if (i < n) dinv[i] = 1.0f / sqrtf((float)(deg[i] + 1));  // +1 self-loop; deg>=1 always
}

// Single-block exclusive scan of deg[0..n) -> offs[0..n], offs[n]=total.
__global__ __launch_bounds__(1024) void k_scan(const int* __restrict__ deg,
                                               int* __restrict__ offs, int n) {
    __shared__ int part[1024];
    int t = threadIdx.x;
    int chunk = (n + 1023) / 1024;
    int b0 = t * chunk, b1 = min(b0 + chunk, n);
    int s = 0;
    for (int i = b0; i < b1; ++i) s += deg[i];
    part[t] = s;
    __syncthreads();
    for (int d = 1; d < 1024; d <<= 1) {
        int v = 0;
        if (t >= d) v = part[t - d];
        __syncthreads();
        part[t] += v;
        __syncthreads();
    }
    int ex = (t == 0) ? 0 : part[t - 1];
    for (int i = b0; i < b1; ++i) { offs[i] = ex; ex += deg[i]; }
    if (t == 1023) offs[n] = ex;
}

__global__ __launch_bounds__(256) void k_fill(const int* __restrict__ src,
                                              const int* __restrict__ dst,
                                              const int* __restrict__ offs,
                                              int* __restrict__ cnt,
                                              int* __restrict__ csr, int E) {
    int e = blockIdx.x * 256 + threadIdx.x;
    if (e < E) {
        int d = dst[e];
        int p = offs[d] + atomicAdd(&cnt[d], 1);
        csr[p] = src[e];
    }
}

// Layer-1 aggregation straight from x (unscaled): out[v] = dinv[v]*(sum_u x[u]*dinv[u] + x[v]*dinv[v])
__global__ __launch_bounds__(256) void k_agg_l1(const float* __restrict__ X,
                                                const float* __restrict__ dinv,
                                                const int* __restrict__ offs,
                                                const int* __restrict__ csr,
                                                float* __restrict__ Y, int n) {
    constexpr int W = 64;
    int t = blockIdx.x * 256 + threadIdx.x;
    int v = t / W, c = t % W;
    if (v >= n) return;
    float dv = dinv[v];
    float sum = X[(size_t)v * W + c] * dv;
    int e = offs[v], re = offs[v + 1];
    for (; e + 4 <= re; e += 4) {
        int u0 = csr[e], u1 = csr[e + 1], u2 = csr[e + 2], u3 = csr[e + 3];
        float a0 = X[(size_t)u0 * W + c] * dinv[u0];
        float a1 = X[(size_t)u1 * W + c] * dinv[u1];
        float a2 = X[(size_t)u2 * W + c] * dinv[u2];
        float a3 = X[(size_t)u3 * W + c] * dinv[u3];
        sum += a0 + a1 + a2 + a3;
    }
    for (; e < re; ++e) { int u = csr[e]; sum += X[(size_t)u * W + c] * dinv[u]; }
    Y[(size_t)v * W + c] = dv * sum;
}

// Generic aggregation over pre-scaled rows S (= (h@W)*dinv[row]):
// out[v] = act(dinv[v]*(sum_u S[u] + S[v]) + b)
template <int W, bool RELU>
__global__ __launch_bounds__(256) void k_agg(const float* __restrict__ S,
                                             const float* __restrict__ dinv,
                                             const int* __restrict__ offs,
                                             const int* __restrict__ csr,
                                             const float* __restrict__ bg,
                                             float* __restrict__ Y, int n) {
    int t = blockIdx.x * 256 + threadIdx.x;
    int v = t / W, c = t % W;
    if (v >= n) return;
    float sum = S[(size_t)v * W + c];  // self-loop term (pre-scaled)
    int e = offs[v], re = offs[v + 1];
    for (; e + 4 <= re; e += 4) {
        int u0 = csr[e], u1 = csr[e + 1], u2 = csr[e + 2], u3 = csr[e + 3];
        float a0 = S[(size_t)u0 * W + c];
        float a1 = S[(size_t)u1 * W + c];
        float a2 = S[(size_t)u2 * W + c];
        float a3 = S[(size_t)u3 * W + c];
        sum += a0 + a1 + a2 + a3;
    }
    for (; e < re; ++e) sum += S[(size_t)csr[e] * W + c];
    float r = dinv[v] * sum + bg[c];
    if (RELU) r = fmaxf(r, 0.0f);
    Y[(size_t)v * W + c] = r;
}

// Tall-skinny GEMM: Y[n,OUT] = X[n,IN] @ Wg[IN,OUT], epilogue:
//   EPI==0: += bias, relu    EPI==1: *= dinv[row]
template <int IN, int OUT, int EPI>
__global__ __launch_bounds__(256) void k_gemm(const float* __restrict__ X,
                                              const float* __restrict__ Wg,
                                              const float* __restrict__ bg,
                                              const float* __restrict__ dinv,
                                              float* __restrict__ Y, int nrows) {
    constexpr int TPR = OUT / 4;          // threads per row (4 cols each)
    constexpr int GROUPS = 256 / TPR;
    constexpr int ROWS = GROUPS * 2;      // 2 rows per thread
    __shared__ __align__(16) float Wl[IN * OUT];
    __shared__ __align__(16) float xl[ROWS * IN];
    __shared__ float bl[OUT];
    int tid = threadIdx.x;
    for (int i = tid; i < IN * OUT; i += 256) Wl[i] = Wg[i];
    if (EPI == 0)
        for (int i = tid; i < OUT; i += 256) bl[i] = bg[i];
    int base = blockIdx.x * ROWS;
    for (int i = tid; i < ROWS * IN; i += 256) {
        int r = base + i / IN;
        xl[i] = (r < nrows) ? X[(size_t)base * IN + i] : 0.0f;
    }
    __syncthreads();
    int g = tid / TPR;
    int c0 = (tid % TPR) * 4;
    int r0 = base + g * 2, r1 = r0 + 1;
    int l0 = (g * 2) * IN, l1 = l0 + IN;
    float4 acc0 = make_float4(0.f, 0.f, 0.f, 0.f);
    float4 acc1 = make_float4(0.f, 0.f, 0.f, 0.f);
#pragma unroll 8
    for (int k = 0; k < IN; ++k) {
        float4 w = *(const float4*)&Wl[k * OUT + c0];
        float a0 = xl[l0 + k], a1 = xl[l1 + k];
        acc0.x += a0 * w.x; acc0.y += a0 * w.y; acc0.z += a0 * w.z; acc0.w += a0 * w.w;
        acc1.x += a1 * w.x; acc1.y += a1 * w.y; acc1.z += a1 * w.z; acc1.w += a1 * w.w;
    }
    if (EPI == 0) {
        float bx = bl[c0], by = bl[c0 + 1], bz = bl[c0 + 2], bw = bl[c0 + 3];
        acc0.x = fmaxf(acc0.x + bx, 0.f); acc0.y = fmaxf(acc0.y + by, 0.f);
        acc0.z = fmaxf(acc0.z + bz, 0.f); acc0.w = fmaxf(acc0.w + bw, 0.f);
        acc1.x = fmaxf(acc1.x + bx, 0.f); acc1.y = fmaxf(acc1.y + by, 0.f);
        acc1.z = fmaxf(acc1.z + bz, 0.f); acc1.w = fmaxf(acc1.w + bw, 0.f);
    } else {
        if (r0 < nrows) { float d0 = dinv[r0]; acc0.x *= d0; acc0.y *= d0; acc0.z *= d0; acc0.w *= d0; }
        if (r1 < nrows) { float d1 = dinv[r1]; acc1.x *= d1; acc1.y *= d1; acc1.z *= d1; acc1.w *= d1; }
    }
    if (r0 < nrows) *(float4*)&Y[(size_t)r0 * OUT + c0] = acc0;
    if (r1 < nrows) *(float4*)&Y[(size_t)r1 * OUT + c0] = acc1;
}

// Final 16->1 GEMM with dinv row-scale: s5[r] = (h4[r,:] . W5) * dinv[r]
__global__ __launch_bounds__(256) void k_gemm5(const float* __restrict__ X,
                                               const float* __restrict__ Wg,
                                               const float* __restrict__ dinv,
                                               float* __restrict__ Y, int n) {
    int r = blockIdx.x * 256 + threadIdx.x;
    if (r >= n) return;
    float acc = 0.f;
#pragma unroll
    for (int k = 0; k < 16; ++k) acc += X[(size_t)r * 16 + k] * Wg[k];
    Y[r] = acc * dinv[r];
}

extern "C" void kernel_launch(void* const* d_in, const int* in_sizes, int n_in,
                              void* d_out, int out_size, void* d_ws, size_t ws_size,
                              hipStream_t stream) {
    const float* x  = (const float*)d_in[0];
    const int*   ei = (const int*)d_in[1];
    const float* W1 = (const float*)d_in[2];  const float* b1 = (const float*)d_in[3];
    const float* W2 = (const float*)d_in[4];  const float* b2 = (const float*)d_in[5];
    const float* W3 = (const float*)d_in[6];  const float* b3 = (const float*)d_in[7];
    const float* W4 = (const float*)d_in[8];  const float* b4 = (const float*)d_in[9];
    const float* W5 = (const float*)d_in[10]; const float* b5 = (const float*)d_in[11];

    const int N = in_sizes[0] / 64;   // 100000
    const int E = in_sizes[1] / 2;    // 1600000
    const int* src = ei;
    const int* dst = ei + E;

    // workspace layout (~111 MB)
    char* ws = (char*)d_ws;
    size_t off = 0;
    auto alloc = [&](size_t bytes) -> void* {
        void* p = ws + off;
        off = (off + bytes + 255) & ~(size_t)255;
        return p;
    };
    int*   deg  = (int*)alloc((size_t)N * 4);
    int*   cnt  = (int*)alloc((size_t)N * 4);
    float* dinv = (float*)alloc((size_t)N * 4);
    int*   offs = (int*)alloc((size_t)(N + 1) * 4);
    int*   csr  = (int*)alloc((size_t)E * 4);
    float* A    = (float*)alloc((size_t)N * 128 * 4);  // h1 (also h3)
    float* B    = (float*)alloc((size_t)N * 64 * 4);   // agg1/s2/s3/s4/s5
    float* C    = (float*)alloc((size_t)N * 64 * 4);   // h2/h4

    hipMemsetAsync(deg, 0, (size_t)N * 4, stream);
    hipMemsetAsync(cnt, 0, (size_t)N * 4, stream);

    k_count<<<(E + 255) / 256, 256, 0, stream>>>(dst, deg, E);
    k_dinv<<<(N + 255) / 256, 256, 0, stream>>>(deg, dinv, N);
    k_scan<<<1, 1024, 0, stream>>>(deg, offs, N);
    k_fill<<<(E + 255) / 256, 256, 0, stream>>>(src, dst, offs, cnt, csr, E);

    // Layer 1: agg1 = A.x (64 wide), then h1 = relu(agg1 @ W1 + b1) (128 wide)
    k_agg_l1<<<(N * 64 + 255) / 256, 256, 0, stream>>>(x, dinv, offs, csr, B, N);
    k_gemm<64, 128, 0><<<(N + 15) / 16, 256, 0, stream>>>(B, W1, b1, nullptr, A, N);
    // Layer 2: s2 = (h1 @ W2)*dinv (64), h2 = relu(A.s2 + b2)
    k_gemm<128, 64, 1><<<(N + 31) / 32, 256, 0, stream>>>(A, W2, nullptr, dinv, B, N);
    k_agg<64, true><<<(N * 64 + 255) / 256, 256, 0, stream>>>(B, dinv, offs, csr, b2, C, N);
    // Layer 3: s3 = (h2 @ W3)*dinv (32), h3 = relu(A.s3 + b3)
    k_gemm<64, 32, 1><<<(N + 63) / 64, 256, 0, stream>>>(C, W3, nullptr, dinv, B, N);
    k_agg<32, true><<<(N * 32 + 255) / 256, 256, 0, stream>>>(B, dinv, offs, csr, b3, A, N);
    // Layer 4: s4 = (h3 @ W4)*dinv (16), h4 = relu(A.s4 + b4)
    k_gemm<32, 16, 1><<<(N + 127) / 128, 256, 0, stream>>>(A, W4, nullptr, dinv, B, N);
    k_agg<16, true><<<(N * 16 + 255) / 256, 256, 0, stream>>>(B, dinv, offs, csr, b4, C, N);
    // Layer 5: s5 = (h4 @ W5)*dinv (1), out = A.s5 + b5 (no relu)
    k_gemm5<<<(N + 255) / 256, 256, 0, stream>>>(C, W5, dinv, B, N);
    k_agg<1, false><<<(N + 255) / 256, 256, 0, stream>>>(B, dinv, offs, csr, b5, (float*)d_out, N);
}

// Round 2
// 519.861 us; speedup vs baseline: 1.2812x; 1.2812x over previous
//
#include <hip/hip_runtime.h>
#include <math.h>

// GCN 5-layer: per layer relu(A @ (h @ W) + b), A = sym-normalized adj w/ self-loops.
// Strategy: CSR-by-dst build (no float atomics), aggregate on the narrow side of
// each GEMM, fold dinv[src] row-scaling into GEMM epilogues. All fp32.
// R2: replaced single-block scan (160us, 24% of runtime) with 3-kernel
// hierarchical scan (tile=2048, 49 blocks).

__global__ __launch_bounds__(256) void k_count(const int* __restrict__ dst,
                                               int* __restrict__ deg, int E) {
    int e = blockIdx.x * 256 + threadIdx.x;
    if (e < E) atomicAdd(&deg[dst[e]], 1);
}

__global__ __launch_bounds__(256) void k_dinv(const int* __restrict__ deg,
                                              float* __restrict__ dinv, int n) {
    int i = blockIdx.x * 256 + threadIdx.x;
    if (i < n) dinv[i] = 1.0f / sqrtf((float)(deg[i] + 1));  // +1 self-loop
}

// ---- hierarchical exclusive scan of deg[0..n) -> offs[0..n] ----
// tile = 2048 elements per block (256 thr x 8)
__global__ __launch_bounds__(256) void k_scan_part(const int* __restrict__ deg,
                                                   int* __restrict__ part, int n) {
    __shared__ int red[256];
    int t = threadIdx.x;
    int base = blockIdx.x * 2048 + t * 8;
    int s = 0;
#pragma unroll
    for (int i = 0; i < 8; ++i) { int idx = base + i; if (idx < n) s += deg[idx]; }
    red[t] = s;
    __syncthreads();
    for (int d = 128; d > 0; d >>= 1) {
        if (t < d) red[t] += red[t + d];
        __syncthreads();
    }
    if (t == 0) part[blockIdx.x] = red[0];
}

// one block; nb <= 256 (N=100k, tile 2048 -> 49). Exclusive-scans part[],
// writes grand total to offs[n].
__global__ __launch_bounds__(256) void k_scan_top(int* __restrict__ part, int nb,
                                                  int* __restrict__ offs, int n) {
    __shared__ int sh[256];
    int t = threadIdx.x;
    int v = (t < nb) ? part[t] : 0;
    sh[t] = v;
    __syncthreads();
    for (int d = 1; d < 256; d <<= 1) {
        int u = (t >= d) ? sh[t - d] : 0;
        __syncthreads();
        sh[t] += u;
        __syncthreads();
    }
    if (t < nb) part[t] = sh[t] - v;       // exclusive prefix of block sums
    if (t == 255) offs[n] = sh[255];       // grand total
}

__global__ __launch_bounds__(256) void k_scan_emit(const int* __restrict__ deg,
                                                   const int* __restrict__ part,
                                                   int* __restrict__ offs, int n) {
    __shared__ int red[256];
    int t = threadIdx.x;
    int base = blockIdx.x * 2048 + t * 8;
    int loc[8];
    int s = 0;
#pragma unroll
    for (int i = 0; i < 8; ++i) {
        int idx = base + i;
        int d = (idx < n) ? deg[idx] : 0;
        loc[i] = s; s += d;
    }
    red[t] = s;
    __syncthreads();
    for (int d = 1; d < 256; d <<= 1) {
        int u = (t >= d) ? red[t - d] : 0;
        __syncthreads();
        red[t] += u;
        __syncthreads();
    }
    int ex = red[t] - s;                   // exclusive prefix of thread sums
    int b = part[blockIdx.x] + ex;
#pragma unroll
    for (int i = 0; i < 8; ++i) {
        int idx = base + i;
        if (idx < n) offs[idx] = b + loc[i];
    }
}
// ---- end scan ----

__global__ __launch_bounds__(256) void k_fill(const int* __restrict__ src,
                                              const int* __restrict__ dst,
                                              const int* __restrict__ offs,
                                              int* __restrict__ cnt,
                                              int* __restrict__ csr, int E) {
    int e = blockIdx.x * 256 + threadIdx.x;
    if (e < E) {
        int d = dst[e];
        int p = offs[d] + atomicAdd(&cnt[d], 1);
        csr[p] = src[e];
    }
}

// Layer-1 aggregation straight from x (unscaled): out[v] = dinv[v]*(sum_u x[u]*dinv[u] + x[v]*dinv[v])
__global__ __launch_bounds__(256) void k_agg_l1(const float* __restrict__ X,
                                                const float* __restrict__ dinv,
                                                const int* __restrict__ offs,
                                                const int* __restrict__ csr,
                                                float* __restrict__ Y, int n) {
    constexpr int W = 64;
    int t = blockIdx.x * 256 + threadIdx.x;
    int v = t / W, c = t % W;
    if (v >= n) return;
    float dv = dinv[v];
    float sum = X[(size_t)v * W + c] * dv;
    int e = offs[v], re = offs[v + 1];
    for (; e + 4 <= re; e += 4) {
        int u0 = csr[e], u1 = csr[e + 1], u2 = csr[e + 2], u3 = csr[e + 3];
        float a0 = X[(size_t)u0 * W + c] * dinv[u0];
        float a1 = X[(size_t)u1 * W + c] * dinv[u1];
        float a2 = X[(size_t)u2 * W + c] * dinv[u2];
        float a3 = X[(size_t)u3 * W + c] * dinv[u3];
        sum += a0 + a1 + a2 + a3;
    }
    for (; e < re; ++e) { int u = csr[e]; sum += X[(size_t)u * W + c] * dinv[u]; }
    Y[(size_t)v * W + c] = dv * sum;
}

// Generic aggregation over pre-scaled rows S (= (h@W)*dinv[row]):
// out[v] = act(dinv[v]*(sum_u S[u] + S[v]) + b)
template <int W, bool RELU>
__global__ __launch_bounds__(256) void k_agg(const float* __restrict__ S,
                                             const float* __restrict__ dinv,
                                             const int* __restrict__ offs,
                                             const int* __restrict__ csr,
                                             const float* __restrict__ bg,
                                             float* __restrict__ Y, int n) {
    int t = blockIdx.x * 256 + threadIdx.x;
    int v = t / W, c = t % W;
    if (v >= n) return;
    float sum = S[(size_t)v * W + c];  // self-loop term (pre-scaled)
    int e = offs[v], re = offs[v + 1];
    for (; e + 4 <= re; e += 4) {
        int u0 = csr[e], u1 = csr[e + 1], u2 = csr[e + 2], u3 = csr[e + 3];
        float a0 = S[(size_t)u0 * W + c];
        float a1 = S[(size_t)u1 * W + c];
        float a2 = S[(size_t)u2 * W + c];
        float a3 = S[(size_t)u3 * W + c];
        sum += a0 + a1 + a2 + a3;
    }
    for (; e < re; ++e) sum += S[(size_t)csr[e] * W + c];
    float r = dinv[v] * sum + bg[c];
    if (RELU) r = fmaxf(r, 0.0f);
    Y[(size_t)v * W + c] = r;
}

// Tall-skinny GEMM: Y[n,OUT] = X[n,IN] @ Wg[IN,OUT], epilogue:
//   EPI==0: += bias, relu    EPI==1: *= dinv[row]
template <int IN, int OUT, int EPI>
__global__ __launch_bounds__(256) void k_gemm(const float* __restrict__ X,
                                              const float* __restrict__ Wg,
                                              const float* __restrict__ bg,
                                              const float* __restrict__ dinv,
                                              float* __restrict__ Y, int nrows) {
    constexpr int TPR = OUT / 4;          // threads per row (4 cols each)
    constexpr int GROUPS = 256 / TPR;
    constexpr int ROWS = GROUPS * 2;      // 2 rows per thread
    __shared__ __align__(16) float Wl[IN * OUT];
    __shared__ __align__(16) float xl[ROWS * IN];
    __shared__ float bl[OUT];
    int tid = threadIdx.x;
    for (int i = tid; i < IN * OUT; i += 256) Wl[i] = Wg[i];
    if (EPI == 0)
        for (int i = tid; i < OUT; i += 256) bl[i] = bg[i];
    int base = blockIdx.x * ROWS;
    for (int i = tid; i < ROWS * IN; i += 256) {
        int r = base + i / IN;
        xl[i] = (r < nrows) ? X[(size_t)base * IN + i] : 0.0f;
    }
    __syncthreads();
    int g = tid / TPR;
    int c0 = (tid % TPR) * 4;
    int r0 = base + g * 2, r1 = r0 + 1;
    int l0 = (g * 2) * IN, l1 = l0 + IN;
    float4 acc0 = make_float4(0.f, 0.f, 0.f, 0.f);
    float4 acc1 = make_float4(0.f, 0.f, 0.f, 0.f);
#pragma unroll 8
    for (int k = 0; k < IN; ++k) {
        float4 w = *(const float4*)&Wl[k * OUT + c0];
        float a0 = xl[l0 + k], a1 = xl[l1 + k];
        acc0.x += a0 * w.x; acc0.y += a0 * w.y; acc0.z += a0 * w.z; acc0.w += a0 * w.w;
        acc1.x += a1 * w.x; acc1.y += a1 * w.y; acc1.z += a1 * w.z; acc1.w += a1 * w.w;
    }
    if (EPI == 0) {
        float bx = bl[c0], by = bl[c0 + 1], bz = bl[c0 + 2], bw = bl[c0 + 3];
        acc0.x = fmaxf(acc0.x + bx, 0.f); acc0.y = fmaxf(acc0.y + by, 0.f);
        acc0.z = fmaxf(acc0.z + bz, 0.f); acc0.w = fmaxf(acc0.w + bw, 0.f);
        acc1.x = fmaxf(acc1.x + bx, 0.f); acc1.y = fmaxf(acc1.y + by, 0.f);
        acc1.z = fmaxf(acc1.z + bz, 0.f); acc1.w = fmaxf(acc1.w + bw, 0.f);
    } else {
        if (r0 < nrows) { float d0 = dinv[r0]; acc0.x *= d0; acc0.y *= d0; acc0.z *= d0; acc0.w *= d0; }
        if (r1 < nrows) { float d1 = dinv[r1]; acc1.x *= d1; acc1.y *= d1; acc1.z *= d1; acc1.w *= d1; }
    }
    if (r0 < nrows) *(float4*)&Y[(size_t)r0 * OUT + c0] = acc0;
    if (r1 < nrows) *(float4*)&Y[(size_t)r1 * OUT + c0] = acc1;
}

// Final 16->1 GEMM with dinv row-scale: s5[r] = (h4[r,:] . W5) * dinv[r]
__global__ __launch_bounds__(256) void k_gemm5(const float* __restrict__ X,
                                               const float* __restrict__ Wg,
                                               const float* __restrict__ dinv,
                                               float* __restrict__ Y, int n) {
    int r = blockIdx.x * 256 + threadIdx.x;
    if (r >= n) return;
    float acc = 0.f;
#pragma unroll
    for (int k = 0; k < 16; ++k) acc += X[(size_t)r * 16 + k] * Wg[k];
    Y[r] = acc * dinv[r];
}

extern "C" void kernel_launch(void* const* d_in, const int* in_sizes, int n_in,
                              void* d_out, int out_size, void* d_ws, size_t ws_size,
                              hipStream_t stream) {
    const float* x  = (const float*)d_in[0];
    const int*   ei = (const int*)d_in[1];
    const float* W1 = (const float*)d_in[2];  const float* b1 = (const float*)d_in[3];
    const float* W2 = (const float*)d_in[4];  const float* b2 = (const float*)d_in[5];
    const float* W3 = (const float*)d_in[6];  const float* b3 = (const float*)d_in[7];
    const float* W4 = (const float*)d_in[8];  const float* b4 = (const float*)d_in[9];
    const float* W5 = (const float*)d_in[10]; const float* b5 = (const float*)d_in[11];

    const int N = in_sizes[0] / 64;   // 100000
    const int E = in_sizes[1] / 2;    // 1600000
    const int* src = ei;
    const int* dst = ei + E;

    // workspace layout (~111 MB)
    char* ws = (char*)d_ws;
    size_t off = 0;
    auto alloc = [&](size_t bytes) -> void* {
        void* p = ws + off;
        off = (off + bytes + 255) & ~(size_t)255;
        return p;
    };
    int*   deg  = (int*)alloc((size_t)N * 4);
    int*   cnt  = (int*)alloc((size_t)N * 4);
    float* dinv = (float*)alloc((size_t)N * 4);
    int*   offs = (int*)alloc((size_t)(N + 1) * 4);
    int*   part = (int*)alloc((size_t)256 * 4);
    int*   csr  = (int*)alloc((size_t)E * 4);
    float* A    = (float*)alloc((size_t)N * 128 * 4);  // h1 (also h3)
    float* B    = (float*)alloc((size_t)N * 64 * 4);   // agg1/s2/s3/s4/s5
    float* C    = (float*)alloc((size_t)N * 64 * 4);   // h2/h4

    hipMemsetAsync(deg, 0, (size_t)N * 4, stream);
    hipMemsetAsync(cnt, 0, (size_t)N * 4, stream);

    const int nb = (N + 2047) / 2048;  // 49 <= 256

    k_count<<<(E + 255) / 256, 256, 0, stream>>>(dst, deg, E);
    k_dinv<<<(N + 255) / 256, 256, 0, stream>>>(deg, dinv, N);
    k_scan_part<<<nb, 256, 0, stream>>>(deg, part, N);
    k_scan_top<<<1, 256, 0, stream>>>(part, nb, offs, N);
    k_scan_emit<<<nb, 256, 0, stream>>>(deg, part, offs, N);
    k_fill<<<(E + 255) / 256, 256, 0, stream>>>(src, dst, offs, cnt, csr, E);

    // Layer 1: agg1 = A.x (64 wide), then h1 = relu(agg1 @ W1 + b1) (128 wide)
    k_agg_l1<<<(N * 64 + 255) / 256, 256, 0, stream>>>(x, dinv, offs, csr, B, N);
    k_gemm<64, 128, 0><<<(N + 15) / 16, 256, 0, stream>>>(B, W1, b1, nullptr, A, N);
    // Layer 2: s2 = (h1 @ W2)*dinv (64), h2 = relu(A.s2 + b2)
    k_gemm<128, 64, 1><<<(N + 31) / 32, 256, 0, stream>>>(A, W2, nullptr, dinv, B, N);
    k_agg<64, true><<<(N * 64 + 255) / 256, 256, 0, stream>>>(B, dinv, offs, csr, b2, C, N);
    // Layer 3: s3 = (h2 @ W3)*dinv (32), h3 = relu(A.s3 + b3)
    k_gemm<64, 32, 1><<<(N + 63) / 64, 256, 0, stream>>>(C, W3, nullptr, dinv, B, N);
    k_agg<32, true><<<(N * 32 + 255) / 256, 256, 0, stream>>>(B, dinv, offs, csr, b3, A, N);
    // Layer 4: s4 = (h3 @ W4)*dinv (16), h4 = relu(A.s4 + b4)
    k_gemm<32, 16, 1><<<(N + 127) / 128, 256, 0, stream>>>(A, W4, nullptr, dinv, B, N);
    k_agg<16, true><<<(N * 16 + 255) / 256, 256, 0, stream>>>(B, dinv, offs, csr, b4, C, N);
    // Layer 5: s5 = (h4 @ W5)*dinv (1), out = A.s5 + b5 (no relu)
    k_gemm5<<<(N + 255) / 256, 256, 0, stream>>>(C, W5, dinv, B, N);
    k_agg<1, false><<<(N + 255) / 256, 256, 0, stream>>>(B, dinv, offs, csr, b5, (float*)d_out, N);
}